// Round 1
// baseline (564.960 us; speedup 1.0000x reference)
//
#include <hip/hip_runtime.h>

#define NEG_SLOPE 0.01f

__device__ __forceinline__ float lrelu(float v) { return v >= 0.0f ? v : NEG_SLOPE * v; }

// Order-preserving float->u32 map: monotone increasing, so unsigned max == float max.
// No real (non-NaN) float maps to 0, so 0 is a safe "empty" sentinel.
__device__ __forceinline__ unsigned encf(float f) {
    unsigned b = __float_as_uint(f);
    return (b & 0x80000000u) ? ~b : (b | 0x80000000u);
}
__device__ __forceinline__ float decf(unsigned u) {
    unsigned b = (u & 0x80000000u) ? (u ^ 0x80000000u) : ~u;
    return __uint_as_float(b);
}

// C[M,128] = epilogue(A[M,128] @ B[128,128] + bias) (+ X)
// DECODE_A: A is the u32 agg buffer; a = (u==0) ? 0 : lrelu(dec(u)+bf[k])
// Tile: 64 rows x 128 cols, BK=64, 256 threads, each thread 8x4 outputs.
template<bool DECODE_A, bool DO_LRELU, bool DO_ADDX>
__global__ __launch_bounds__(256) void gemm_k128(
    const float* __restrict__ A, const unsigned* __restrict__ Au,
    const float* __restrict__ bfv, const float* __restrict__ B,
    const float* __restrict__ bias, const float* __restrict__ Xadd,
    float* __restrict__ Cout, int M)
{
    __shared__ float As[64 * 64];
    __shared__ float Bs[64 * 128];
    const int tid = threadIdx.x;
    const int rg = tid >> 5;     // 0..7  -> row group of 8
    const int cg = tid & 31;     // 0..31 -> col group of 4
    const int row0 = blockIdx.x * 64;

    float acc[8][4];
#pragma unroll
    for (int i = 0; i < 8; ++i)
#pragma unroll
        for (int j = 0; j < 4; ++j) acc[i][j] = 0.0f;

    for (int k0 = 0; k0 < 128; k0 += 64) {
        // stage A tile (64x64 floats), 1024 float4 over 256 threads
#pragma unroll
        for (int i = 0; i < 4; ++i) {
            int lin = tid + 256 * i;
            int r = lin >> 4;
            int c4 = (lin & 15) * 4;
            int grow = row0 + r;
            float4 v = make_float4(0.f, 0.f, 0.f, 0.f);
            if (grow < M) {
                if (DECODE_A) {
                    const unsigned* p = Au + (size_t)grow * 128 + k0 + c4;
                    int kk = k0 + c4;
                    unsigned u0 = p[0], u1 = p[1], u2 = p[2], u3 = p[3];
                    v.x = u0 ? lrelu(decf(u0) + bfv[kk + 0]) : 0.f;
                    v.y = u1 ? lrelu(decf(u1) + bfv[kk + 1]) : 0.f;
                    v.z = u2 ? lrelu(decf(u2) + bfv[kk + 2]) : 0.f;
                    v.w = u3 ? lrelu(decf(u3) + bfv[kk + 3]) : 0.f;
                } else {
                    v = *(const float4*)(A + (size_t)grow * 128 + k0 + c4);
                }
            }
            *(float4*)&As[r * 64 + c4] = v;
        }
        // stage B tile (64x128 floats), 2048 float4 over 256 threads
#pragma unroll
        for (int i = 0; i < 8; ++i) {
            int lin = tid + 256 * i;
            int r = lin >> 5;
            int c4 = (lin & 31) * 4;
            *(float4*)&Bs[r * 128 + c4] = *(const float4*)(B + (size_t)(k0 + r) * 128 + c4);
        }
        __syncthreads();
#pragma unroll
        for (int kk = 0; kk < 64; ++kk) {
            float4 bv = *(const float4*)&Bs[kk * 128 + cg * 4];
#pragma unroll
            for (int i = 0; i < 8; ++i) {
                float a = As[(rg * 8 + i) * 64 + kk];  // broadcast within wave: free
                acc[i][0] += a * bv.x;
                acc[i][1] += a * bv.y;
                acc[i][2] += a * bv.z;
                acc[i][3] += a * bv.w;
            }
        }
        __syncthreads();
    }

#pragma unroll
    for (int i = 0; i < 8; ++i) {
        int row = row0 + rg * 8 + i;
        if (row >= M) continue;
        int col = cg * 4;
        float4 o;
        float* ov = &o.x;
#pragma unroll
        for (int j = 0; j < 4; ++j) {
            float v = acc[i][j];
            if (bias) v += bias[col + j];
            if (DO_LRELU) v = lrelu(v);
            if (DO_ADDX) v += Xadd[(size_t)row * 128 + col + j];
            ov[j] = v;
        }
        *(float4*)(Cout + (size_t)row * 128 + col) = o;
    }
}

// delta[node,0..2] = tanh(h1[node,:] @ Wh2 + bh2), one wave per node
__global__ __launch_bounds__(256) void delta_kernel(
    const float* __restrict__ h1, const float* __restrict__ Wh2,
    const float* __restrict__ bh2, float* __restrict__ delta, int M)
{
    int wave = threadIdx.x >> 6;
    int lane = threadIdx.x & 63;
    int node = blockIdx.x * 4 + wave;
    if (node >= M) return;
    float a0 = 0.f, a1 = 0.f, a2 = 0.f;
#pragma unroll
    for (int t = 0; t < 2; ++t) {
        int k = lane + t * 64;
        float v = h1[(size_t)node * 128 + k];
        a0 += v * Wh2[k * 3 + 0];
        a1 += v * Wh2[k * 3 + 1];
        a2 += v * Wh2[k * 3 + 2];
    }
#pragma unroll
    for (int off = 32; off > 0; off >>= 1) {
        a0 += __shfl_down(a0, off);
        a1 += __shfl_down(a1, off);
        a2 += __shfl_down(a2, off);
    }
    if (lane == 0) {
        delta[node * 3 + 0] = tanhf(a0 + bh2[0]);
        delta[node * 3 + 1] = tanhf(a1 + bh2[1]);
        delta[node * 3 + 2] = tanhf(a2 + bh2[2]);
    }
}

// Per edge: z[c] = y[src][c] + rel . Wf_rel[:,c]; aggU[dst][c] = umax(enc(z))
// 2 edges per 256-thread block-iteration (128 channels each; one edge per wave-pair)
__global__ __launch_bounds__(256) void edge_kernel(
    const int* __restrict__ ei, const float* __restrict__ pos,
    const float* __restrict__ delta, const float* __restrict__ y,
    const float* __restrict__ Wf, unsigned* __restrict__ aggU, int E)
{
    const int c = threadIdx.x & 127;
    const int half = threadIdx.x >> 7;
    const float w0 = Wf[c], w1 = Wf[128 + c], w2 = Wf[256 + c];
    for (int e = blockIdx.x * 2 + half; e < E; e += gridDim.x * 2) {
        int src = ei[e];
        int dst = ei[E + e];
        float r0 = pos[src * 3 + 0] - pos[dst * 3 + 0] + delta[dst * 3 + 0];
        float r1 = pos[src * 3 + 1] - pos[dst * 3 + 1] + delta[dst * 3 + 1];
        float r2 = pos[src * 3 + 2] - pos[dst * 3 + 2] + delta[dst * 3 + 2];
        float z = y[(size_t)src * 128 + c] + r0 * w0 + r1 * w1 + r2 * w2;
        atomicMax(aggU + (size_t)dst * 128 + c, encf(z));
    }
}

extern "C" void kernel_launch(void* const* d_in, const int* in_sizes, int n_in,
                              void* d_out, int out_size, void* d_ws, size_t ws_size,
                              hipStream_t stream)
{
    const float* x   = (const float*)d_in[0];
    const float* pos = (const float*)d_in[1];
    const int*   ei  = (const int*)d_in[2];
    const float* Wh1 = (const float*)d_in[3];
    const float* bh1 = (const float*)d_in[4];
    const float* Wh2 = (const float*)d_in[5];
    const float* bh2 = (const float*)d_in[6];
    const float* Wf  = (const float*)d_in[7];
    const float* bf  = (const float*)d_in[8];
    const float* Wg1 = (const float*)d_in[9];
    const float* bg1 = (const float*)d_in[10];
    const float* Wg2 = (const float*)d_in[11];
    const float* bg2 = (const float*)d_in[12];
    float* out = (float*)d_out;

    const int M = in_sizes[0] / 128;   // 50000 nodes
    const int E = in_sizes[2] / 2;     // 800000 edges
    const size_t NB = (size_t)M * 128 * sizeof(float);

    char* ws = (char*)d_ws;
    float*    buf_a = (float*)ws;                 // h1, then y (y GEMM reads x, not h1)
    unsigned* aggU  = (unsigned*)(ws + NB);       // agg (u32), then mid in-place
    float*    mid   = (float*)(ws + NB);
    float*    delta = (float*)(ws + 2 * NB);      // [M,3]

    hipMemsetAsync(aggU, 0, NB, stream);          // sentinel 0 == empty segment

    const int gb = (M + 63) / 64;
    // h1 = lrelu(x@Wh1 + bh1)
    gemm_k128<false, true, false><<<gb, 256, 0, stream>>>(
        x, nullptr, nullptr, Wh1, bh1, nullptr, buf_a, M);
    // delta = tanh(h1@Wh2 + bh2)
    delta_kernel<<<(M + 3) / 4, 256, 0, stream>>>(buf_a, Wh2, bh2, delta, M);
    // y = x @ Wf_x  (rows 3..130 of Wf; bias folded into decode later)
    gemm_k128<false, false, false><<<gb, 256, 0, stream>>>(
        x, nullptr, nullptr, Wf + 3 * 128, nullptr, nullptr, buf_a, M);
    // scatter-max of raw z into aggU
    edge_kernel<<<8192, 256, 0, stream>>>(ei, pos, delta, buf_a, Wf, aggU, E);
    // mid = lrelu( decode(aggU) @ Wg1 + bg1 )   (decode = lrelu(z_max + bf), 0 if empty)
    gemm_k128<true, true, false><<<gb, 256, 0, stream>>>(
        nullptr, aggU, bf, Wg1, bg1, nullptr, mid, M);
    // out = mid @ Wg2 + bg2 + x
    gemm_k128<false, false, true><<<gb, 256, 0, stream>>>(
        mid, nullptr, nullptr, Wg2, bg2, x, out, M);
}

// Round 2
// 473.348 us; speedup vs baseline: 1.1935x; 1.1935x over previous
//
#include <hip/hip_runtime.h>
#include <cfloat>

#define NEG_SLOPE 0.01f

__device__ __forceinline__ float lrelu(float v) { return v >= 0.0f ? v : NEG_SLOPE * v; }

// ---------------------------------------------------------------------------
// GEMM: C[M,128] = epilogue(A[M,128] @ B[128,128] + bias) (+ X) (+ pos.w)
// DECODE_A: A is agg (float, -FLT_MAX sentinel for empty segments);
//           a = empty ? 0 : lrelu(agg + q[row].w[k] + bf[k])
// DO_POSW : epilogue adds pos[row] . Wf[0:3][col]   (builds y' = x@Wf_x + pos.w)
// Tile: 64 rows x 128 cols, BK=64, 256 threads, each thread 8x4 outputs.
// ---------------------------------------------------------------------------
template<bool DECODE_A, bool DO_POSW, bool DO_LRELU, bool DO_ADDX>
__global__ __launch_bounds__(256) void gemm_k128(
    const float* __restrict__ A, const float* __restrict__ Aagg,
    const float* __restrict__ qv, const float* __restrict__ Wf3,
    const float* __restrict__ bfv, const float* __restrict__ posv,
    const float* __restrict__ B, const float* __restrict__ bias,
    const float* __restrict__ Xadd, float* __restrict__ Cout, int M)
{
    __shared__ float As[64 * 64];
    __shared__ float Bs[64 * 128];
    const int tid = threadIdx.x;
    const int rg = tid >> 5;     // 0..7  -> row group of 8
    const int cg = tid & 31;     // 0..31 -> col group of 4
    const int row0 = blockIdx.x * 64;

    float acc[8][4];
#pragma unroll
    for (int i = 0; i < 8; ++i)
#pragma unroll
        for (int j = 0; j < 4; ++j) acc[i][j] = 0.0f;

    for (int k0 = 0; k0 < 128; k0 += 64) {
        // stage A tile (64x64 floats), 1024 float4 over 256 threads
#pragma unroll
        for (int i = 0; i < 4; ++i) {
            int lin = tid + 256 * i;
            int r = lin >> 4;
            int c4 = (lin & 15) * 4;
            int grow = row0 + r;
            float4 v = make_float4(0.f, 0.f, 0.f, 0.f);
            if (grow < M) {
                if (DECODE_A) {
                    float4 u = *(const float4*)(Aagg + (size_t)grow * 128 + k0 + c4);
                    float q0 = qv[grow * 3 + 0], q1 = qv[grow * 3 + 1], q2 = qv[grow * 3 + 2];
                    int kk = k0 + c4;
                    float* uv = &u.x;
                    float* vv = &v.x;
#pragma unroll
                    for (int j = 0; j < 4; ++j) {
                        float t = q0 * Wf3[kk + j] + q1 * Wf3[128 + kk + j] + q2 * Wf3[256 + kk + j];
                        vv[j] = (uv[j] == -FLT_MAX) ? 0.f : lrelu(uv[j] + t + bfv[kk + j]);
                    }
                } else {
                    v = *(const float4*)(A + (size_t)grow * 128 + k0 + c4);
                }
            }
            *(float4*)&As[r * 64 + c4] = v;
        }
        // stage B tile (64x128 floats), 2048 float4 over 256 threads
#pragma unroll
        for (int i = 0; i < 8; ++i) {
            int lin = tid + 256 * i;
            int r = lin >> 5;
            int c4 = (lin & 31) * 4;
            *(float4*)&Bs[r * 128 + c4] = *(const float4*)(B + (size_t)(k0 + r) * 128 + c4);
        }
        __syncthreads();
#pragma unroll
        for (int kk = 0; kk < 64; ++kk) {
            float4 bv = *(const float4*)&Bs[kk * 128 + cg * 4];
#pragma unroll
            for (int i = 0; i < 8; ++i) {
                float a = As[(rg * 8 + i) * 64 + kk];
                acc[i][0] += a * bv.x;
                acc[i][1] += a * bv.y;
                acc[i][2] += a * bv.z;
                acc[i][3] += a * bv.w;
            }
        }
        __syncthreads();
    }

#pragma unroll
    for (int i = 0; i < 8; ++i) {
        int row = row0 + rg * 8 + i;
        if (row >= M) continue;
        int col = cg * 4;
        float p0 = 0.f, p1 = 0.f, p2 = 0.f;
        if (DO_POSW) { p0 = posv[row * 3 + 0]; p1 = posv[row * 3 + 1]; p2 = posv[row * 3 + 2]; }
        float4 o;
        float* ov = &o.x;
#pragma unroll
        for (int j = 0; j < 4; ++j) {
            float v = acc[i][j];
            if (bias) v += bias[col + j];
            if (DO_LRELU) v = lrelu(v);
            if (DO_POSW) v += p0 * Wf3[col + j] + p1 * Wf3[128 + col + j] + p2 * Wf3[256 + col + j];
            if (DO_ADDX) v += Xadd[(size_t)row * 128 + col + j];
            ov[j] = v;
        }
        *(float4*)(Cout + (size_t)row * 128 + col) = o;
    }
}

// q[node] = tanh(h1[node,:] @ Wh2 + bh2) - pos[node]   (one wave per node)
__global__ __launch_bounds__(256) void q_kernel(
    const float* __restrict__ h1, const float* __restrict__ Wh2,
    const float* __restrict__ bh2, const float* __restrict__ pos,
    float* __restrict__ q, int M)
{
    int wave = threadIdx.x >> 6;
    int lane = threadIdx.x & 63;
    int node = blockIdx.x * 4 + wave;
    if (node >= M) return;
    float a0 = 0.f, a1 = 0.f, a2 = 0.f;
#pragma unroll
    for (int t = 0; t < 2; ++t) {
        int k = lane + t * 64;
        float v = h1[(size_t)node * 128 + k];
        a0 += v * Wh2[k * 3 + 0];
        a1 += v * Wh2[k * 3 + 1];
        a2 += v * Wh2[k * 3 + 2];
    }
#pragma unroll
    for (int off = 32; off > 0; off >>= 1) {
        a0 += __shfl_down(a0, off);
        a1 += __shfl_down(a1, off);
        a2 += __shfl_down(a2, off);
    }
    if (lane == 0) {
        q[node * 3 + 0] = tanhf(a0 + bh2[0]) - pos[node * 3 + 0];
        q[node * 3 + 1] = tanhf(a1 + bh2[1]) - pos[node * 3 + 1];
        q[node * 3 + 2] = tanhf(a2 + bh2[2]) - pos[node * 3 + 2];
    }
}

// ---- CSR build --------------------------------------------------------------
__global__ __launch_bounds__(256) void hist_kernel(
    const int* __restrict__ ei, int* __restrict__ deg, int E)
{
    int e = blockIdx.x * 256 + threadIdx.x;
    if (e < E) atomicAdd(&deg[ei[E + e]], 1);
}

__global__ __launch_bounds__(256) void scan1_kernel(
    const int* __restrict__ deg, int* __restrict__ partial, int M)
{
    __shared__ int s[256];
    int i = blockIdx.x * 256 + threadIdx.x;
    int v = (i < M) ? deg[i] : 0;
    s[threadIdx.x] = v;
    __syncthreads();
    for (int d = 128; d > 0; d >>= 1) {
        if (threadIdx.x < d) s[threadIdx.x] += s[threadIdx.x + d];
        __syncthreads();
    }
    if (threadIdx.x == 0) partial[blockIdx.x] = s[0];
}

__global__ __launch_bounds__(256) void scan2_kernel(
    int* __restrict__ partial, int* __restrict__ offs, int SB, int M, int E)
{
    __shared__ int s[256];
    int t = threadIdx.x;
    int v = (t < SB) ? partial[t] : 0;
    s[t] = v;
    __syncthreads();
    for (int d = 1; d < 256; d <<= 1) {
        int a = (t >= d) ? s[t - d] : 0;
        __syncthreads();
        s[t] += a;
        __syncthreads();
    }
    if (t < SB) partial[t] = s[t] - v;  // exclusive
    if (t == 0) offs[M] = E;
}

__global__ __launch_bounds__(256) void scan3_kernel(
    const int* __restrict__ deg, const int* __restrict__ partial,
    int* __restrict__ offs, int* __restrict__ cursor, int M)
{
    __shared__ int s[256];
    int t = threadIdx.x;
    int i = blockIdx.x * 256 + t;
    int v = (i < M) ? deg[i] : 0;
    s[t] = v;
    __syncthreads();
    for (int d = 1; d < 256; d <<= 1) {
        int a = (t >= d) ? s[t - d] : 0;
        __syncthreads();
        s[t] += a;
        __syncthreads();
    }
    if (i < M) {
        int o = partial[blockIdx.x] + s[t] - v;
        offs[i] = o;
        cursor[i] = o;
    }
}

__global__ __launch_bounds__(256) void scatter_kernel(
    const int* __restrict__ ei, int* __restrict__ cursor,
    int* __restrict__ srcs, int E)
{
    int e = blockIdx.x * 256 + threadIdx.x;
    if (e < E) {
        int d = ei[E + e];
        int p = atomicAdd(&cursor[d], 1);
        srcs[p] = ei[e];
    }
}

// ---- aggregation: agg[i,:] = max over incoming srcs of y'[s,:] --------------
// one wave per node; lane owns 2 channels (float2); -FLT_MAX if no edges
__global__ __launch_bounds__(256) void agg_kernel(
    const int* __restrict__ offs, const int* __restrict__ srcs,
    const float* __restrict__ y, float* __restrict__ agg, int M)
{
    int wave = threadIdx.x >> 6;
    int lane = threadIdx.x & 63;
    int node = blockIdx.x * 4 + wave;
    if (node >= M) return;
    int o0 = offs[node], o1 = offs[node + 1];
    float2 acc = make_float2(-FLT_MAX, -FLT_MAX);
    const float2* yp = (const float2*)y;
    int j = o0;
    for (; j + 1 < o1; j += 2) {
        int s0 = srcs[j], s1 = srcs[j + 1];
        float2 v0 = yp[(size_t)s0 * 64 + lane];
        float2 v1 = yp[(size_t)s1 * 64 + lane];
        acc.x = fmaxf(acc.x, fmaxf(v0.x, v1.x));
        acc.y = fmaxf(acc.y, fmaxf(v0.y, v1.y));
    }
    if (j < o1) {
        int s = srcs[j];
        float2 v = yp[(size_t)s * 64 + lane];
        acc.x = fmaxf(acc.x, v.x);
        acc.y = fmaxf(acc.y, v.y);
    }
    ((float2*)agg)[(size_t)node * 64 + lane] = acc;
}

extern "C" void kernel_launch(void* const* d_in, const int* in_sizes, int n_in,
                              void* d_out, int out_size, void* d_ws, size_t ws_size,
                              hipStream_t stream)
{
    const float* x   = (const float*)d_in[0];
    const float* pos = (const float*)d_in[1];
    const int*   ei  = (const int*)d_in[2];
    const float* Wh1 = (const float*)d_in[3];
    const float* bh1 = (const float*)d_in[4];
    const float* Wh2 = (const float*)d_in[5];
    const float* bh2 = (const float*)d_in[6];
    const float* Wf  = (const float*)d_in[7];
    const float* bf  = (const float*)d_in[8];
    const float* Wg1 = (const float*)d_in[9];
    const float* bg1 = (const float*)d_in[10];
    const float* Wg2 = (const float*)d_in[11];
    const float* bg2 = (const float*)d_in[12];
    float* out = (float*)d_out;

    const int M = in_sizes[0] / 128;   // 50000 nodes
    const int E = in_sizes[2] / 2;     // 800000 edges
    const size_t NB = (size_t)M * 128 * sizeof(float);
    const int SB = (M + 255) / 256;    // scan blocks (<=256 required; 196 here)

    char* ws = (char*)d_ws;
    size_t off = 0;
    auto alloc = [&](size_t bytes) { void* p = ws + off; off += (bytes + 15) & ~15ull; return p; };
    float* buf_a  = (float*)alloc(NB);              // h1 -> y' -> mid
    float* agg    = (float*)alloc(NB);
    float* q      = (float*)alloc((size_t)M * 3 * sizeof(float));
    int*   deg    = (int*)alloc((size_t)M * sizeof(int));
    int*   offs   = (int*)alloc((size_t)(M + 1) * sizeof(int));
    int*   cursor = (int*)alloc((size_t)M * sizeof(int));
    int*   part   = (int*)alloc(256 * sizeof(int));
    int*   srcs   = (int*)alloc((size_t)E * sizeof(int));

    const int gb = (M + 63) / 64;
    const int ge = (E + 255) / 256;

    // CSR build (independent of GEMMs until scatter)
    hipMemsetAsync(deg, 0, (size_t)M * sizeof(int), stream);
    hist_kernel<<<ge, 256, 0, stream>>>(ei, deg, E);
    scan1_kernel<<<SB, 256, 0, stream>>>(deg, part, M);
    scan2_kernel<<<1, 256, 0, stream>>>(part, offs, SB, M, E);
    scan3_kernel<<<SB, 256, 0, stream>>>(deg, part, offs, cursor, M);
    scatter_kernel<<<ge, 256, 0, stream>>>(ei, cursor, srcs, E);

    // h1 = lrelu(x@Wh1 + bh1)
    gemm_k128<false, false, true, false><<<gb, 256, 0, stream>>>(
        x, nullptr, nullptr, nullptr, nullptr, nullptr, Wh1, bh1, nullptr, buf_a, M);
    // q = tanh(h1@Wh2 + bh2) - pos
    q_kernel<<<(M + 3) / 4, 256, 0, stream>>>(buf_a, Wh2, bh2, pos, q, M);
    // y' = x @ Wf_x + pos.w   (rows 3..130 of Wf; pos.w in epilogue)
    gemm_k128<false, true, false, false><<<gb, 256, 0, stream>>>(
        x, nullptr, nullptr, Wf, nullptr, pos, Wf + 3 * 128, nullptr, nullptr, buf_a, M);
    // agg[i] = max over incoming edges of y'[src]
    agg_kernel<<<(M + 3) / 4, 256, 0, stream>>>(offs, srcs, buf_a, agg, M);
    // mid = lrelu( decode(agg) @ Wg1 + bg1 ), decode = lrelu(agg + q.w + bf), 0 if empty
    gemm_k128<true, false, true, false><<<gb, 256, 0, stream>>>(
        nullptr, agg, q, Wf, bf, nullptr, Wg1, bg1, nullptr, buf_a, M);
    // out = mid @ Wg2 + bg2 + x
    gemm_k128<false, false, false, true><<<gb, 256, 0, stream>>>(
        buf_a, nullptr, nullptr, nullptr, nullptr, nullptr, Wg2, bg2, x, out, M);
}

// Round 4
// 343.475 us; speedup vs baseline: 1.6448x; 1.3781x over previous
//
#include <hip/hip_runtime.h>
#include <cfloat>
#include <cmath>

#define NEG_SLOPE 0.01f

typedef __attribute__((ext_vector_type(8))) short short8;
typedef __attribute__((ext_vector_type(4))) float f32x4;

__device__ __forceinline__ float lrelu(float v) { return v >= 0.0f ? v : NEG_SLOPE * v; }

// f32 -> bf16 round-to-nearest-even (monotone; identity on exact bf16 values)
__device__ __forceinline__ ushort f2b(float f) {
    unsigned u = __float_as_uint(f);
    u += 0x7fffu + ((u >> 16) & 1u);
    return (ushort)(u >> 16);
}
__device__ __forceinline__ float b2f(ushort s) { return __uint_as_float(((unsigned)s) << 16); }
__device__ __forceinline__ void split2(float v, ushort& hi, ushort& lo) {
    hi = f2b(v);
    lo = f2b(v - b2f(hi));
}

// ---------------- prep: weights -> bf16, transposed [n][k] ----------------
// WT[mat][n*128+k]: mat 0=Wh1, 1=Wf rows 3..130, 2=Wg1, 3=Wg2
__global__ __launch_bounds__(256) void wprep_kernel(
    const float* __restrict__ Wh1, const float* __restrict__ Wf,
    const float* __restrict__ Wg1, const float* __restrict__ Wg2,
    ushort* __restrict__ WT)
{
    int t = blockIdx.x * 256 + threadIdx.x;   // 4 * 16384
    int mat = t >> 14;
    int idx = t & 16383;
    int n = idx >> 7, k = idx & 127;
    float v;
    if (mat == 0)      v = Wh1[k * 128 + n];
    else if (mat == 1) v = Wf[(k + 3) * 128 + n];
    else if (mat == 2) v = Wg1[k * 128 + n];
    else               v = Wg2[k * 128 + n];
    WT[t - idx + n * 128 + k] = f2b(v);
}

// ---------------- MFMA GEMM skeleton ----------------
// block = 256 thr = 4 waves; tile 64 rows x 128 cols; K = 128 (4 steps of 32).
// wave w covers rows [w*16, w*16+16); lane: qd = L>>4, ln = L&15.
// A operand split hi/lo (2 MFMAs) for near-f32 A-side precision.
// a_frag: A[m = w*16+ln][k = ks*32+qd*8+j]   (As_hi/As_lo, stride 136 bf16)
// b_frag: WT[n = nt*16+ln][k = ks*32+qd*8+j] (Bs, stride 136 bf16)
// D:      C[m = w*16+qd*4+r][n = nt*16+ln] = acc[nt][r]

#define GEMM_CORE(ACC)                                                          \
    {                                                                           \
        _Pragma("unroll")                                                       \
        for (int ks = 0; ks < 4; ++ks) {                                        \
            short8 ah = *(const short8*)&As_hi[(w * 16 + ln) * 136 + ks * 32 + qd * 8]; \
            short8 al = *(const short8*)&As_lo[(w * 16 + ln) * 136 + ks * 32 + qd * 8]; \
            _Pragma("unroll")                                                   \
            for (int nt = 0; nt < 8; ++nt) {                                    \
                short8 bfr = *(const short8*)&Bs[(nt * 16 + ln) * 136 + ks * 32 + qd * 8]; \
                ACC[nt] = __builtin_amdgcn_mfma_f32_16x16x32_bf16(al, bfr, ACC[nt], 0, 0, 0); \
                ACC[nt] = __builtin_amdgcn_mfma_f32_16x16x32_bf16(ah, bfr, ACC[nt], 0, 0, 0); \
            }                                                                   \
        }                                                                       \
    }

#define STAGE_B(WTP)                                                            \
    {                                                                           \
        _Pragma("unroll")                                                       \
        for (int i = 0; i < 8; ++i) {                                           \
            int c = tid + 256 * i;                                              \
            int r = c >> 4, col8 = (c & 15) * 8;                                \
            *(uint4*)&Bs[r * 136 + col8] = *(const uint4*)((WTP) + r * 128 + col8); \
        }                                                                       \
    }

// stage A tile (64x128) from f32 source, split hi/lo. 2048 float4 chunks.
#define STAGE_A_F32(SRC)                                                        \
    {                                                                           \
        _Pragma("unroll")                                                       \
        for (int i = 0; i < 8; ++i) {                                           \
            int c = tid + 256 * i;                                              \
            int r = c >> 5, col4 = (c & 31) * 4;                                \
            float4 v = make_float4(0.f, 0.f, 0.f, 0.f);                         \
            if (row0 + r < M) v = *(const float4*)((SRC) + (size_t)(row0 + r) * 128 + col4); \
            ushort4 h, l;                                                       \
            split2(v.x, h.x, l.x); split2(v.y, h.y, l.y);                       \
            split2(v.z, h.z, l.z); split2(v.w, h.w, l.w);                       \
            *(ushort4*)&As_hi[r * 136 + col4] = h;                              \
            *(ushort4*)&As_lo[r * 136 + col4] = l;                              \
        }                                                                       \
    }

// ---------------- fused: h1 = lrelu(x@Wh1+bh1); q = tanh(h1@Wh2+bh2) - pos ----
__global__ __launch_bounds__(256) void h1q_kernel(
    const float* __restrict__ x, const ushort* __restrict__ Wh1T,
    const float* __restrict__ bh1, const float* __restrict__ Wh2,
    const float* __restrict__ bh2, const float* __restrict__ pos,
    float* __restrict__ q, int M)
{
    __shared__ ushort As_hi[64 * 136];
    __shared__ ushort As_lo[64 * 136];
    __shared__ ushort Bs[128 * 136];
    const int tid = threadIdx.x;
    const int w = tid >> 6, L = tid & 63, qd = L >> 4, ln = L & 15;
    const int row0 = blockIdx.x * 64;

    STAGE_A_F32(x);
    STAGE_B(Wh1T);
    __syncthreads();

    f32x4 acc[8];
#pragma unroll
    for (int nt = 0; nt < 8; ++nt) acc[nt] = (f32x4){0.f, 0.f, 0.f, 0.f};
    GEMM_CORE(acc);
    __syncthreads();

    float* h1s = (float*)Bs;  // 64 x 132 f32 (33792 B <= 34816 B)
#pragma unroll
    for (int nt = 0; nt < 8; ++nt) {
        int n = nt * 16 + ln;
        float bias = bh1[n];
#pragma unroll
        for (int r = 0; r < 4; ++r)
            h1s[(w * 16 + qd * 4 + r) * 132 + n] = lrelu(acc[nt][r] + bias);
    }
    __syncthreads();

    int row = tid & 63, c = tid >> 6;
    if (c < 3 && row0 + row < M) {
        float s = 0.f;
#pragma unroll
        for (int k4 = 0; k4 < 32; ++k4) {
            float4 h = *(const float4*)&h1s[row * 132 + k4 * 4];
            s += h.x * Wh2[(k4 * 4 + 0) * 3 + c] + h.y * Wh2[(k4 * 4 + 1) * 3 + c]
               + h.z * Wh2[(k4 * 4 + 2) * 3 + c] + h.w * Wh2[(k4 * 4 + 3) * 3 + c];
        }
        q[(row0 + row) * 3 + c] = tanhf(s + bh2[c]) - pos[(row0 + row) * 3 + c];
    }
}

// ---------------- y' = x@Wf_x + pos.Wf_rel  (f32 out) ----------------
__global__ __launch_bounds__(256) void yprime_kernel(
    const float* __restrict__ x, const ushort* __restrict__ WfxT,
    const float* __restrict__ Wf, const float* __restrict__ pos,
    float* __restrict__ y, int M)
{
    __shared__ ushort As_hi[64 * 136];
    __shared__ ushort As_lo[64 * 136];
    __shared__ ushort Bs[128 * 136];
    const int tid = threadIdx.x;
    const int w = tid >> 6, L = tid & 63, qd = L >> 4, ln = L & 15;
    const int row0 = blockIdx.x * 64;

    STAGE_A_F32(x);
    STAGE_B(WfxT);
    __syncthreads();

    f32x4 acc[8];
#pragma unroll
    for (int nt = 0; nt < 8; ++nt) acc[nt] = (f32x4){0.f, 0.f, 0.f, 0.f};
    GEMM_CORE(acc);
    __syncthreads();

    float* yS = (float*)Bs;  // 64 x 132 f32
#pragma unroll
    for (int r = 0; r < 4; ++r) {
        int m = w * 16 + qd * 4 + r;
        int gm = row0 + m;
        float p0 = 0.f, p1 = 0.f, p2 = 0.f;
        if (gm < M) { p0 = pos[gm * 3]; p1 = pos[gm * 3 + 1]; p2 = pos[gm * 3 + 2]; }
#pragma unroll
        for (int nt = 0; nt < 8; ++nt) {
            int n = nt * 16 + ln;
            yS[m * 132 + n] = acc[nt][r] + p0 * Wf[n] + p1 * Wf[128 + n] + p2 * Wf[256 + n];
        }
    }
    __syncthreads();
#pragma unroll
    for (int i = 0; i < 8; ++i) {   // coalesced copy-out: 2048 float4 chunks
        int c = tid + 256 * i;
        int r = c >> 5, col4 = (c & 31) * 4;
        if (row0 + r < M)
            *(float4*)(y + (size_t)(row0 + r) * 128 + col4) = *(const float4*)&yS[r * 132 + col4];
    }
}

// ---------------- fused: decode(agg) @ Wg1 -> lrelu -> @ Wg2 + bg2 + x --------
__global__ __launch_bounds__(256) void midout_kernel(
    const float* __restrict__ agg, const float* __restrict__ qv,
    const float* __restrict__ Wf, const float* __restrict__ bfv,
    const ushort* __restrict__ Wg1T, const float* __restrict__ bg1,
    const ushort* __restrict__ Wg2T, const float* __restrict__ bg2,
    const float* __restrict__ x, float* __restrict__ out, int M)
{
    __shared__ ushort As_hi[64 * 136];
    __shared__ ushort As_lo[64 * 136];
    __shared__ ushort Bs[128 * 136];
    const int tid = threadIdx.x;
    const int w = tid >> 6, L = tid & 63, qd = L >> 4, ln = L & 15;
    const int row0 = blockIdx.x * 64;

    // decode agg tile -> hi/lo A stage. 2048 float4 chunks.
#pragma unroll
    for (int i = 0; i < 8; ++i) {
        int c = tid + 256 * i;
        int r = c >> 5, col4 = (c & 31) * 4;
        int gm = row0 + r;
        ushort4 h = make_ushort4(0, 0, 0, 0), l = make_ushort4(0, 0, 0, 0);
        if (gm < M) {
            float4 u = *(const float4*)(agg + (size_t)gm * 128 + col4);
            float q0 = qv[gm * 3], q1 = qv[gm * 3 + 1], q2 = qv[gm * 3 + 2];
            float* uv = &u.x;
            ushort* hv = &h.x;
            ushort* lv = &l.x;
#pragma unroll
            for (int j = 0; j < 4; ++j) {
                int k = col4 + j;
                float dec = 0.f;
                if (uv[j] != -FLT_MAX)  // -FLT_MAX sentinel = empty segment
                    dec = lrelu(uv[j] + q0 * Wf[k] + q1 * Wf[128 + k] + q2 * Wf[256 + k] + bfv[k]);
                split2(dec, hv[j], lv[j]);
            }
        }
        *(ushort4*)&As_hi[r * 136 + col4] = h;
        *(ushort4*)&As_lo[r * 136 + col4] = l;
    }
    STAGE_B(Wg1T);
    __syncthreads();

    f32x4 macc[8];
#pragma unroll
    for (int nt = 0; nt < 8; ++nt) macc[nt] = (f32x4){0.f, 0.f, 0.f, 0.f};
    GEMM_CORE(macc);
    __syncthreads();   // all waves done reading As/Bs

    // mid -> As (hi/lo), restage Bs = Wg2T
#pragma unroll
    for (int nt = 0; nt < 8; ++nt) {
        int n = nt * 16 + ln;
        float bias = bg1[n];
#pragma unroll
        for (int r = 0; r < 4; ++r) {
            float mid = lrelu(macc[nt][r] + bias);
            ushort h, lo;
            split2(mid, h, lo);
            As_hi[(w * 16 + qd * 4 + r) * 136 + n] = h;
            As_lo[(w * 16 + qd * 4 + r) * 136 + n] = lo;
        }
    }
    STAGE_B(Wg2T);
    __syncthreads();

    f32x4 acc2[8];
#pragma unroll
    for (int nt = 0; nt < 8; ++nt) acc2[nt] = (f32x4){0.f, 0.f, 0.f, 0.f};
    GEMM_CORE(acc2);
    __syncthreads();

    float* outS = (float*)Bs;  // 64 x 132
#pragma unroll
    for (int r = 0; r < 4; ++r) {
        int m = w * 16 + qd * 4 + r;
        int gm = row0 + m;
#pragma unroll
        for (int nt = 0; nt < 8; ++nt) {
            int n = nt * 16 + ln;
            float xv = (gm < M) ? x[(size_t)gm * 128 + n] : 0.f;
            outS[m * 132 + n] = acc2[nt][r] + bg2[n] + xv;
        }
    }
    __syncthreads();
#pragma unroll
    for (int i = 0; i < 8; ++i) {   // coalesced copy-out
        int c = tid + 256 * i;
        int r = c >> 5, col4 = (c & 31) * 4;
        if (row0 + r < M)
            *(float4*)(out + (size_t)(row0 + r) * 128 + col4) = *(const float4*)&outS[r * 132 + col4];
    }
}

// ---------------- CSR build ----------------
__global__ __launch_bounds__(256) void hist_kernel(
    const int* __restrict__ ei, int* __restrict__ deg, int E)
{
    int e = blockIdx.x * 256 + threadIdx.x;
    if (e < E) atomicAdd(&deg[ei[E + e]], 1);
}

__global__ __launch_bounds__(256) void scan1_kernel(
    const int* __restrict__ deg, int* __restrict__ partial, int M)
{
    __shared__ int s[256];
    int i = blockIdx.x * 256 + threadIdx.x;
    int v = (i < M) ? deg[i] : 0;
    s[threadIdx.x] = v;
    __syncthreads();
    for (int d = 128; d > 0; d >>= 1) {
        if (threadIdx.x < d) s[threadIdx.x] += s[threadIdx.x + d];
        __syncthreads();
    }
    if (threadIdx.x == 0) partial[blockIdx.x] = s[0];
}

__global__ __launch_bounds__(256) void scan2_kernel(
    int* __restrict__ partial, int* __restrict__ offs, int SB, int M, int E)
{
    __shared__ int s[256];
    int t = threadIdx.x;
    int v = (t < SB) ? partial[t] : 0;
    s[t] = v;
    __syncthreads();
    for (int d = 1; d < 256; d <<= 1) {
        int a = (t >= d) ? s[t - d] : 0;
        __syncthreads();
        s[t] += a;
        __syncthreads();
    }
    if (t < SB) partial[t] = s[t] - v;  // exclusive
    if (t == 0) offs[M] = E;
}

__global__ __launch_bounds__(256) void scan3_kernel(
    const int* __restrict__ deg, const int* __restrict__ partial,
    int* __restrict__ offs, int* __restrict__ cursor, int M)
{
    __shared__ int s[256];
    int t = threadIdx.x;
    int i = blockIdx.x * 256 + t;
    int v = (i < M) ? deg[i] : 0;
    s[t] = v;
    __syncthreads();
    for (int d = 1; d < 256; d <<= 1) {
        int a = (t >= d) ? s[t - d] : 0;
        __syncthreads();
        s[t] += a;
        __syncthreads();
    }
    if (i < M) {
        int o = partial[blockIdx.x] + s[t] - v;
        offs[i] = o;
        cursor[i] = o;
    }
}

__global__ __launch_bounds__(256) void scatter_kernel(
    const int* __restrict__ ei, int* __restrict__ cursor,
    int* __restrict__ srcs, int E)
{
    int e = blockIdx.x * 256 + threadIdx.x;
    if (e < E) {
        int d = ei[E + e];
        int p = atomicAdd(&cursor[d], 1);
        srcs[p] = ei[e];
    }
}

// ---- aggregation: agg[i,:] = max over incoming srcs of y'[s,:] (f32) --------
__global__ __launch_bounds__(256) void agg_kernel(
    const int* __restrict__ offs, const int* __restrict__ srcs,
    const float* __restrict__ y, float* __restrict__ agg, int M)
{
    int wave = threadIdx.x >> 6;
    int lane = threadIdx.x & 63;
    int node = blockIdx.x * 4 + wave;
    if (node >= M) return;
    int o0 = offs[node], o1 = offs[node + 1];
    float2 acc = make_float2(-FLT_MAX, -FLT_MAX);
    const float2* yp = (const float2*)y;
    int j = o0;
    for (; j + 1 < o1; j += 2) {
        int s0 = srcs[j], s1 = srcs[j + 1];
        float2 v0 = yp[(size_t)s0 * 64 + lane];
        float2 v1 = yp[(size_t)s1 * 64 + lane];
        acc.x = fmaxf(acc.x, fmaxf(v0.x, v1.x));
        acc.y = fmaxf(acc.y, fmaxf(v0.y, v1.y));
    }
    if (j < o1) {
        int s = srcs[j];
        float2 v = yp[(size_t)s * 64 + lane];
        acc.x = fmaxf(acc.x, v.x);
        acc.y = fmaxf(acc.y, v.y);
    }
    ((float2*)agg)[(size_t)node * 64 + lane] = acc;
}

extern "C" void kernel_launch(void* const* d_in, const int* in_sizes, int n_in,
                              void* d_out, int out_size, void* d_ws, size_t ws_size,
                              hipStream_t stream)
{
    const float* x   = (const float*)d_in[0];
    const float* pos = (const float*)d_in[1];
    const int*   ei  = (const int*)d_in[2];
    const float* Wh1 = (const float*)d_in[3];
    const float* bh1 = (const float*)d_in[4];
    const float* Wh2 = (const float*)d_in[5];
    const float* bh2 = (const float*)d_in[6];
    const float* Wf  = (const float*)d_in[7];
    const float* bf  = (const float*)d_in[8];
    const float* Wg1 = (const float*)d_in[9];
    const float* bg1 = (const float*)d_in[10];
    const float* Wg2 = (const float*)d_in[11];
    const float* bg2 = (const float*)d_in[12];
    float* out = (float*)d_out;

    const int M = in_sizes[0] / 128;   // 50000
    const int E = in_sizes[2] / 2;     // 800000
    const size_t NB = (size_t)M * 128 * sizeof(float);
    const int SB = (M + 255) / 256;    // 196 (<=256 required by scan2)

    char* ws = (char*)d_ws;
    size_t off = 0;
    auto alloc = [&](size_t bytes) { void* p = ws + off; off += (bytes + 15) & ~15ull; return p; };
    float*  yb   = (float*)alloc(NB);
    float*  agg  = (float*)alloc(NB);
    ushort* WT   = (ushort*)alloc(4 * 16384 * sizeof(ushort));
    float*  q    = (float*)alloc((size_t)M * 3 * sizeof(float));
    int* deg     = (int*)alloc((size_t)M * sizeof(int));
    int* offs    = (int*)alloc((size_t)(M + 1) * sizeof(int));
    int* cursor  = (int*)alloc((size_t)M * sizeof(int));
    int* part    = (int*)alloc(256 * sizeof(int));
    int* srcs    = (int*)alloc((size_t)E * sizeof(int));

    const int gb = (M + 63) / 64;       // 782
    const int ge = (E + 255) / 256;

    // CSR build
    hipMemsetAsync(deg, 0, (size_t)M * sizeof(int), stream);
    hist_kernel<<<ge, 256, 0, stream>>>(ei, deg, E);
    scan1_kernel<<<SB, 256, 0, stream>>>(deg, part, M);
    scan2_kernel<<<1, 256, 0, stream>>>(part, offs, SB, M, E);
    scan3_kernel<<<SB, 256, 0, stream>>>(deg, part, offs, cursor, M);
    scatter_kernel<<<ge, 256, 0, stream>>>(ei, cursor, srcs, E);

    // prep
    wprep_kernel<<<256, 256, 0, stream>>>(Wh1, Wf, Wg1, Wg2, WT);

    // fused pipeline
    h1q_kernel<<<gb, 256, 0, stream>>>(x, WT, bh1, Wh2, bh2, pos, q, M);
    yprime_kernel<<<gb, 256, 0, stream>>>(x, WT + 16384, Wf, pos, yb, M);
    agg_kernel<<<(M + 3) / 4, 256, 0, stream>>>(offs, srcs, yb, agg, M);
    midout_kernel<<<gb, 256, 0, stream>>>(agg, q, Wf, bf,
                                          WT + 2 * 16384, bg1,
                                          WT + 3 * 16384, bg2, x, out, M);
}

// Round 5
// 285.773 us; speedup vs baseline: 1.9770x; 1.2019x over previous
//
#include <hip/hip_runtime.h>
#include <cfloat>
#include <cmath>

#define NEG_SLOPE 0.01f

typedef __attribute__((ext_vector_type(8))) short short8;
typedef __attribute__((ext_vector_type(4))) float f32x4;

__device__ __forceinline__ float lrelu(float v) { return v >= 0.0f ? v : NEG_SLOPE * v; }

// f32 -> bf16 round-to-nearest-even (monotone; identity on exact bf16 values)
__device__ __forceinline__ ushort f2b(float f) {
    unsigned u = __float_as_uint(f);
    u += 0x7fffu + ((u >> 16) & 1u);
    return (ushort)(u >> 16);
}
__device__ __forceinline__ float b2f(ushort s) { return __uint_as_float(((unsigned)s) << 16); }

// split 8 consecutive f32 into hi/lo bf16 fragments (register-resident)
__device__ __forceinline__ void split8(const float* v, short8& hi, short8& lo) {
#pragma unroll
    for (int j = 0; j < 8; ++j) {
        ushort h = f2b(v[j]);
        hi[j] = (short)h;
        lo[j] = (short)f2b(v[j] - b2f(h));
    }
}

// ---------------- prep: weights -> bf16, transposed [n][k] ----------------
// WT[mat][n*128+k]: mat 0=Wh1, 1=Wf rows 3..130, 2=Wg1, 3=Wg2
__global__ __launch_bounds__(256) void wprep_kernel(
    const float* __restrict__ Wh1, const float* __restrict__ Wf,
    const float* __restrict__ Wg1, const float* __restrict__ Wg2,
    ushort* __restrict__ WT)
{
    int t = blockIdx.x * 256 + threadIdx.x;   // 4 * 16384
    int mat = t >> 14;
    int idx = t & 16383;
    int n = idx >> 7, k = idx & 127;
    float v;
    if (mat == 0)      v = Wh1[k * 128 + n];
    else if (mat == 1) v = Wf[(k + 3) * 128 + n];
    else if (mat == 2) v = Wg1[k * 128 + n];
    else               v = Wg2[k * 128 + n];
    WT[t - idx + n * 128 + k] = f2b(v);
}

// ---------------- MFMA GEMM skeleton ----------------
// block = 256 thr = 4 waves; tile 64 rows x 128 cols; K = 128 (4 steps of 32).
// wave w covers rows [w*16, w*16+16); lane: qd = L>>4, ln = L&15.
// A-operand lives in REGISTERS (hi/lo split, 2 MFMAs per fragment):
//   a_frag[ks]: A[m = w*16+ln][k = ks*32+qd*8+j]   (loaded straight from global)
// b_frag: WT[n = nt*16+ln][k = ks*32+qd*8+j]       (LDS Bs, stride 136 bf16)
// D:      C[m = w*16+qd*4+r][n = nt*16+ln] = acc[nt][r]

#define GEMM_CORE_REG(ACC, AH, AL)                                              \
    {                                                                           \
        _Pragma("unroll")                                                       \
        for (int ks = 0; ks < 4; ++ks) {                                        \
            _Pragma("unroll")                                                   \
            for (int nt = 0; nt < 8; ++nt) {                                    \
                short8 bfr = *(const short8*)&Bs[(nt * 16 + ln) * 136 + ks * 32 + qd * 8]; \
                ACC[nt] = __builtin_amdgcn_mfma_f32_16x16x32_bf16(AL[ks], bfr, ACC[nt], 0, 0, 0); \
                ACC[nt] = __builtin_amdgcn_mfma_f32_16x16x32_bf16(AH[ks], bfr, ACC[nt], 0, 0, 0); \
            }                                                                   \
        }                                                                       \
    }

#define STAGE_B(WTP)                                                            \
    {                                                                           \
        _Pragma("unroll")                                                       \
        for (int i = 0; i < 8; ++i) {                                           \
            int c = tid + 256 * i;                                              \
            int r = c >> 4, col8 = (c & 15) * 8;                                \
            *(uint4*)&Bs[r * 136 + col8] = *(const uint4*)((WTP) + r * 128 + col8); \
        }                                                                       \
    }

// ---- fused: h1=lrelu(x@Wh1+bh1); q=tanh(h1@Wh2+bh2)-pos; y'=x@Wfx+pos.Wrel --
__global__ __launch_bounds__(256) void hy_kernel(
    const float* __restrict__ x, const ushort* __restrict__ Wh1T,
    const float* __restrict__ bh1, const float* __restrict__ Wh2,
    const float* __restrict__ bh2, const ushort* __restrict__ WfxT,
    const float* __restrict__ Wf, const float* __restrict__ pos,
    float* __restrict__ q, ushort* __restrict__ yb, int M)
{
    __shared__ ushort Bs[128 * 136];   // 34816 B
    __shared__ ushort yS[64 * 128];    // 16384 B  (51200 total -> 3 blocks/CU)
    const int tid = threadIdx.x;
    const int w = tid >> 6, L = tid & 63, qd = L >> 4, ln = L & 15;
    const int row0 = blockIdx.x * 64;
    const int arow = row0 + w * 16 + ln;

    // A fragments straight from global x, hi/lo split in regs
    short8 ah[4], al[4];
    {
        const float* base = x + (size_t)((arow < M) ? arow : 0) * 128 + qd * 8;
        float vb[8];
#pragma unroll
        for (int ks = 0; ks < 4; ++ks) {
            float4 v0 = make_float4(0.f, 0.f, 0.f, 0.f), v1 = v0;
            if (arow < M) {
                v0 = *(const float4*)(base + ks * 32);
                v1 = *(const float4*)(base + ks * 32 + 4);
            }
            vb[0] = v0.x; vb[1] = v0.y; vb[2] = v0.z; vb[3] = v0.w;
            vb[4] = v1.x; vb[5] = v1.y; vb[6] = v1.z; vb[7] = v1.w;
            split8(vb, ah[ks], al[ks]);
        }
    }

    STAGE_B(Wh1T);
    __syncthreads();
    f32x4 acc1[8];
#pragma unroll
    for (int nt = 0; nt < 8; ++nt) acc1[nt] = (f32x4){0.f, 0.f, 0.f, 0.f};
    GEMM_CORE_REG(acc1, ah, al);
    __syncthreads();

    STAGE_B(WfxT);
    __syncthreads();
    f32x4 acc2[8];
#pragma unroll
    for (int nt = 0; nt < 8; ++nt) acc2[nt] = (f32x4){0.f, 0.f, 0.f, 0.f};
    GEMM_CORE_REG(acc2, ah, al);
    __syncthreads();

    // h1 (f32) into Bs region; y' (bf16) into yS
    float* h1s = (float*)Bs;   // 64 x 132 f32 = 33792 B
#pragma unroll
    for (int nt = 0; nt < 8; ++nt) {
        int n = nt * 16 + ln;
        float bias = bh1[n];
#pragma unroll
        for (int r = 0; r < 4; ++r)
            h1s[(w * 16 + qd * 4 + r) * 132 + n] = lrelu(acc1[nt][r] + bias);
    }
#pragma unroll
    for (int r = 0; r < 4; ++r) {
        int m = w * 16 + qd * 4 + r;
        int gm = row0 + m;
        float p0 = 0.f, p1 = 0.f, p2 = 0.f;
        if (gm < M) { p0 = pos[gm * 3]; p1 = pos[gm * 3 + 1]; p2 = pos[gm * 3 + 2]; }
#pragma unroll
        for (int nt = 0; nt < 8; ++nt) {
            int n = nt * 16 + ln;
            yS[m * 128 + n] = f2b(acc2[nt][r] + p0 * Wf[n] + p1 * Wf[128 + n] + p2 * Wf[256 + n]);
        }
    }
    __syncthreads();

    // q reduction (threads 0..191)
    int row = tid & 63, cc = tid >> 6;
    if (cc < 3 && row0 + row < M) {
        float s = 0.f;
#pragma unroll
        for (int k4 = 0; k4 < 32; ++k4) {
            float4 h = *(const float4*)&h1s[row * 132 + k4 * 4];
            s += h.x * Wh2[(k4 * 4 + 0) * 3 + cc] + h.y * Wh2[(k4 * 4 + 1) * 3 + cc]
               + h.z * Wh2[(k4 * 4 + 2) * 3 + cc] + h.w * Wh2[(k4 * 4 + 3) * 3 + cc];
        }
        q[(row0 + row) * 3 + cc] = tanhf(s + bh2[cc]) - pos[(row0 + row) * 3 + cc];
    }
    // y' copy-out: 1024 x 16B chunks
#pragma unroll
    for (int i = 0; i < 4; ++i) {
        int c = tid + 256 * i;
        int r = c >> 4, col8 = (c & 15) * 8;
        if (row0 + r < M)
            *(uint4*)(yb + (size_t)(row0 + r) * 128 + col8) = *(const uint4*)&yS[r * 128 + col8];
    }
}

// ---- fused: decode(agg) @ Wg1 -> lrelu -> @ Wg2 + bg2 + x -------------------
__global__ __launch_bounds__(256) void midout_kernel(
    const ushort* __restrict__ aggb, const float* __restrict__ qv,
    const float* __restrict__ Wf, const float* __restrict__ bfv,
    const ushort* __restrict__ Wg1T, const float* __restrict__ bg1,
    const ushort* __restrict__ Wg2T, const float* __restrict__ bg2,
    const float* __restrict__ x, float* __restrict__ out, int M)
{
    __shared__ ushort Bs[128 * 136];   // 34816 B
    __shared__ float  Ms[64 * 132];    // 33792 B (68608 total -> 2 blocks/CU)
    const int tid = threadIdx.x;
    const int w = tid >> 6, L = tid & 63, qd = L >> 4, ln = L & 15;
    const int row0 = blockIdx.x * 64;
    const int arow = row0 + w * 16 + ln;

    // A fragments: load agg bf16 row, decode, split in regs
    short8 ah[4], al[4];
    {
        bool ok = arow < M;
        const ushort* base = aggb + (size_t)(ok ? arow : 0) * 128 + qd * 8;
        float q0 = 0.f, q1 = 0.f, q2 = 0.f;
        if (ok) { q0 = qv[arow * 3]; q1 = qv[arow * 3 + 1]; q2 = qv[arow * 3 + 2]; }
        float vb[8];
#pragma unroll
        for (int ks = 0; ks < 4; ++ks) {
            union { uint4 u; ushort s[8]; } a;
            a.u = ok ? *(const uint4*)(base + ks * 32) : make_uint4(0xFF80FF80u, 0xFF80FF80u, 0xFF80FF80u, 0xFF80FF80u);
#pragma unroll
            for (int j = 0; j < 8; ++j) {
                int k = ks * 32 + qd * 8 + j;
                float dec = 0.f;
                if (a.s[j] != 0xFF80u)   // bf16 -inf sentinel = empty segment
                    dec = lrelu(b2f(a.s[j]) + q0 * Wf[k] + q1 * Wf[128 + k] + q2 * Wf[256 + k] + bfv[k]);
                vb[j] = dec;
            }
            split8(vb, ah[ks], al[ks]);
        }
    }

    STAGE_B(Wg1T);
    __syncthreads();
    f32x4 macc[8];
#pragma unroll
    for (int nt = 0; nt < 8; ++nt) macc[nt] = (f32x4){0.f, 0.f, 0.f, 0.f};
    GEMM_CORE_REG(macc, ah, al);
    __syncthreads();

    // mid (f32) -> Ms; restage Bs = Wg2T
#pragma unroll
    for (int nt = 0; nt < 8; ++nt) {
        int n = nt * 16 + ln;
        float bias = bg1[n];
#pragma unroll
        for (int r = 0; r < 4; ++r)
            Ms[(w * 16 + qd * 4 + r) * 132 + n] = lrelu(macc[nt][r] + bias);
    }
    STAGE_B(Wg2T);
    __syncthreads();

    // second A fragments from Ms (f32), split in regs
    short8 ah2[4], al2[4];
    {
        const float* base = &Ms[(w * 16 + ln) * 132 + qd * 8];
        float vb[8];
#pragma unroll
        for (int ks = 0; ks < 4; ++ks) {
            float4 v0 = *(const float4*)(base + ks * 32);
            float4 v1 = *(const float4*)(base + ks * 32 + 4);
            vb[0] = v0.x; vb[1] = v0.y; vb[2] = v0.z; vb[3] = v0.w;
            vb[4] = v1.x; vb[5] = v1.y; vb[6] = v1.z; vb[7] = v1.w;
            split8(vb, ah2[ks], al2[ks]);
        }
    }
    f32x4 acc2[8];
#pragma unroll
    for (int nt = 0; nt < 8; ++nt) acc2[nt] = (f32x4){0.f, 0.f, 0.f, 0.f};
    GEMM_CORE_REG(acc2, ah2, al2);
    __syncthreads();   // all waves done with Ms fragment reads

    // raw acc -> Ms; bg2 + x folded into coalesced copy-out
#pragma unroll
    for (int r = 0; r < 4; ++r) {
        int m = w * 16 + qd * 4 + r;
#pragma unroll
        for (int nt = 0; nt < 8; ++nt)
            Ms[m * 132 + nt * 16 + ln] = acc2[nt][r];
    }
    __syncthreads();
#pragma unroll
    for (int i = 0; i < 8; ++i) {
        int c = tid + 256 * i;
        int r = c >> 5, col4 = (c & 31) * 4;
        int gr = row0 + r;
        if (gr < M) {
            float4 o = *(const float4*)&Ms[r * 132 + col4];
            float4 bv = *(const float4*)(bg2 + col4);
            float4 xv = *(const float4*)(x + (size_t)gr * 128 + col4);
            o.x += bv.x + xv.x; o.y += bv.y + xv.y;
            o.z += bv.z + xv.z; o.w += bv.w + xv.w;
            *(float4*)(out + (size_t)gr * 128 + col4) = o;
        }
    }
}

// ---------------- CSR build ----------------
__global__ __launch_bounds__(256) void hist_kernel(
    const int* __restrict__ ei, int* __restrict__ deg, int E)
{
    int e = blockIdx.x * 256 + threadIdx.x;
    if (e < E) atomicAdd(&deg[ei[E + e]], 1);
}

__global__ __launch_bounds__(256) void scan1_kernel(
    const int* __restrict__ deg, int* __restrict__ partial, int M)
{
    __shared__ int s[256];
    int i = blockIdx.x * 256 + threadIdx.x;
    int v = (i < M) ? deg[i] : 0;
    s[threadIdx.x] = v;
    __syncthreads();
    for (int d = 128; d > 0; d >>= 1) {
        if (threadIdx.x < d) s[threadIdx.x] += s[threadIdx.x + d];
        __syncthreads();
    }
    if (threadIdx.x == 0) partial[blockIdx.x] = s[0];
}

__global__ __launch_bounds__(256) void scan2_kernel(
    int* __restrict__ partial, int* __restrict__ offs, int SB, int M, int E)
{
    __shared__ int s[256];
    int t = threadIdx.x;
    int v = (t < SB) ? partial[t] : 0;
    s[t] = v;
    __syncthreads();
    for (int d = 1; d < 256; d <<= 1) {
        int a = (t >= d) ? s[t - d] : 0;
        __syncthreads();
        s[t] += a;
        __syncthreads();
    }
    if (t < SB) partial[t] = s[t] - v;  // exclusive
    if (t == 0) offs[M] = E;
}

__global__ __launch_bounds__(256) void scan3_kernel(
    const int* __restrict__ deg, const int* __restrict__ partial,
    int* __restrict__ offs, int* __restrict__ cursor, int M)
{
    __shared__ int s[256];
    int t = threadIdx.x;
    int i = blockIdx.x * 256 + t;
    int v = (i < M) ? deg[i] : 0;
    s[t] = v;
    __syncthreads();
    for (int d = 1; d < 256; d <<= 1) {
        int a = (t >= d) ? s[t - d] : 0;
        __syncthreads();
        s[t] += a;
        __syncthreads();
    }
    if (i < M) {
        int o = partial[blockIdx.x] + s[t] - v;
        offs[i] = o;
        cursor[i] = o;
    }
}

__global__ __launch_bounds__(256) void scatter_kernel(
    const int* __restrict__ ei, int* __restrict__ cursor,
    int* __restrict__ srcs, int E)
{
    int e = blockIdx.x * 256 + threadIdx.x;
    if (e < E) {
        int d = ei[E + e];
        int p = atomicAdd(&cursor[d], 1);
        srcs[p] = ei[e];
    }
}

// ---- aggregation: agg[i,:] = max over incoming srcs of y'[s,:] (bf16) -------
// one wave per node; lane owns 2 channels packed in a uint
__global__ __launch_bounds__(256) void agg_kernel(
    const int* __restrict__ offs, const int* __restrict__ srcs,
    const ushort* __restrict__ yb, ushort* __restrict__ aggb, int M)
{
    int wave = threadIdx.x >> 6;
    int lane = threadIdx.x & 63;
    int node = blockIdx.x * 4 + wave;
    if (node >= M) return;
    int o0 = offs[node], o1 = offs[node + 1];
    float a0 = -INFINITY, a1 = -INFINITY;
    const uint* yp = (const uint*)yb;
    int j = o0;
    for (; j + 3 < o1; j += 4) {
        int s0 = srcs[j], s1 = srcs[j + 1], s2 = srcs[j + 2], s3 = srcs[j + 3];
        uint u0 = yp[(size_t)s0 * 64 + lane];
        uint u1 = yp[(size_t)s1 * 64 + lane];
        uint u2 = yp[(size_t)s2 * 64 + lane];
        uint u3 = yp[(size_t)s3 * 64 + lane];
        a0 = fmaxf(a0, fmaxf(fmaxf(__uint_as_float(u0 << 16), __uint_as_float(u1 << 16)),
                             fmaxf(__uint_as_float(u2 << 16), __uint_as_float(u3 << 16))));
        a1 = fmaxf(a1, fmaxf(fmaxf(__uint_as_float(u0 & 0xFFFF0000u), __uint_as_float(u1 & 0xFFFF0000u)),
                             fmaxf(__uint_as_float(u2 & 0xFFFF0000u), __uint_as_float(u3 & 0xFFFF0000u))));
    }
    for (; j < o1; ++j) {
        uint u = yp[(size_t)srcs[j] * 64 + lane];
        a0 = fmaxf(a0, __uint_as_float(u << 16));
        a1 = fmaxf(a1, __uint_as_float(u & 0xFFFF0000u));
    }
    // values are exact bf16 (or -inf) -> repack without rounding
    uint pk = (__float_as_uint(a0) >> 16) | (__float_as_uint(a1) & 0xFFFF0000u);
    ((uint*)aggb)[(size_t)node * 64 + lane] = pk;
}

extern "C" void kernel_launch(void* const* d_in, const int* in_sizes, int n_in,
                              void* d_out, int out_size, void* d_ws, size_t ws_size,
                              hipStream_t stream)
{
    const float* x   = (const float*)d_in[0];
    const float* pos = (const float*)d_in[1];
    const int*   ei  = (const int*)d_in[2];
    const float* Wh1 = (const float*)d_in[3];
    const float* bh1 = (const float*)d_in[4];
    const float* Wh2 = (const float*)d_in[5];
    const float* bh2 = (const float*)d_in[6];
    const float* Wf  = (const float*)d_in[7];
    const float* bf  = (const float*)d_in[8];
    const float* Wg1 = (const float*)d_in[9];
    const float* bg1 = (const float*)d_in[10];
    const float* Wg2 = (const float*)d_in[11];
    const float* bg2 = (const float*)d_in[12];
    float* out = (float*)d_out;

    const int M = in_sizes[0] / 128;   // 50000
    const int E = in_sizes[2] / 2;     // 800000
    const int SB = (M + 255) / 256;    // 196 (<=256 required by scan2)

    char* ws = (char*)d_ws;
    size_t off = 0;
    auto alloc = [&](size_t bytes) { void* p = ws + off; off += (bytes + 15) & ~15ull; return p; };
    ushort* yb   = (ushort*)alloc((size_t)M * 128 * sizeof(ushort));
    ushort* aggb = (ushort*)alloc((size_t)M * 128 * sizeof(ushort));
    ushort* WT   = (ushort*)alloc(4 * 16384 * sizeof(ushort));
    float*  q    = (float*)alloc((size_t)M * 3 * sizeof(float));
    int* deg     = (int*)alloc((size_t)M * sizeof(int));
    int* offs    = (int*)alloc((size_t)(M + 1) * sizeof(int));
    int* cursor  = (int*)alloc((size_t)M * sizeof(int));
    int* part    = (int*)alloc(256 * sizeof(int));
    int* srcs    = (int*)alloc((size_t)E * sizeof(int));

    const int gb = (M + 63) / 64;       // 782
    const int ge = (E + 255) / 256;

    // CSR build
    hipMemsetAsync(deg, 0, (size_t)M * sizeof(int), stream);
    hist_kernel<<<ge, 256, 0, stream>>>(ei, deg, E);
    scan1_kernel<<<SB, 256, 0, stream>>>(deg, part, M);
    scan2_kernel<<<1, 256, 0, stream>>>(part, offs, SB, M, E);
    scan3_kernel<<<SB, 256, 0, stream>>>(deg, part, offs, cursor, M);
    scatter_kernel<<<ge, 256, 0, stream>>>(ei, cursor, srcs, E);

    // prep
    wprep_kernel<<<256, 256, 0, stream>>>(Wh1, Wf, Wg1, Wg2, WT);

    // fused pipeline
    hy_kernel<<<gb, 256, 0, stream>>>(x, WT, bh1, Wh2, bh2,
                                      WT + 16384, Wf, pos, q, yb, M);
    agg_kernel<<<(M + 3) / 4, 256, 0, stream>>>(offs, srcs, yb, aggb, M);
    midout_kernel<<<gb, 256, 0, stream>>>(aggb, q, Wf, bf,
                                          WT + 2 * 16384, bg1,
                                          WT + 3 * 16384, bg2, x, out, M);
}